// Round 7
// baseline (804.327 us; speedup 1.0000x reference)
//
#include <hip/hip_runtime.h>

typedef unsigned short u16;
using bf16x8 = __attribute__((ext_vector_type(8))) __bf16;
using f32x4  = __attribute__((ext_vector_type(4))) float;

typedef const void __attribute__((address_space(1))) gvoid_t;
typedef void __attribute__((address_space(3))) lvoid_t;

#define NL 2
#define Bd 2
#define Ld 1024
#define Dd_ 1024
#define Ed 2048
#define Nd 16
#define TOK (Bd*Ld)          // 2048 tokens
#define VPAD 50432           // 197 * 256
#define VREAL 50280
#define NCHUNK 16
#define CLEN 64
#define XLD 4096             // combined skip|xin row stride

__device__ __forceinline__ u16 f2bf(float f) {
    union { float f; unsigned u; } v; v.f = f;
    unsigned u = v.u;
    unsigned r = (u + 0x7fffu + ((u >> 16) & 1u)) >> 16;
    return (u16)r;
}
__device__ __forceinline__ float siluf(float x) { return x / (1.f + __expf(-x)); }
__device__ __forceinline__ float softplusf(float z) {
    return (z > 15.f) ? z : log1pf(__expf(z));
}

// ---------------- one-shot weight conversion (all regions) ----------------
__global__ void k_convert_all(const float* __restrict__ lmw, const float* __restrict__ lskip,
                              const float* __restrict__ linw, const float* __restrict__ loutw,
                              const float* __restrict__ lWd2, const float* __restrict__ lWd1,
                              const float* __restrict__ lWB, const float* __restrict__ lWC,
                              u16* __restrict__ lm_bf, u16* __restrict__ wsi_bf,
                              u16* __restrict__ wout_bf, u16* __restrict__ wd2_bf,
                              u16* __restrict__ wsml_bf) {
    int g = blockIdx.x * 256 + threadIdx.x;
    const float* src = nullptr; u16* dst = nullptr;
    if (g < 12910592) {
        dst = lm_bf + (size_t)g * 4;
        if (g < 12871680) src = lmw + (size_t)g * 4;
    } else if (g < 15007744) {
        int i = g - 12910592;
        int layer = i >> 20;
        int within = i & 1048575;
        int mat = within >> 19;
        int idx = within & 524287;
        src = (mat ? linw : lskip) + ((size_t)layer << 21) + ((size_t)idx * 4);
        dst = wsi_bf + ((size_t)layer << 22) + ((size_t)mat << 21) + ((size_t)idx * 4);
    } else if (g < 16056320) {
        int i = g - 15007744;
        src = loutw + (size_t)i * 4; dst = wout_bf + (size_t)i * 4;
    } else if (g < 16121856) {
        int i = g - 16056320;
        src = lWd2 + (size_t)i * 4; dst = wd2_bf + (size_t)i * 4;
    } else {
        int i = g - 16121856;
        int layer = i >> 16;
        int j = i & 65535;
        int col = (j * 4) & 2047;
        int r = (j * 4) >> 11;
        const float* s2 = nullptr;
        if (r < 64) s2 = lWd1 + ((size_t)layer * 64 + r) * 2048;
        else if (r < 80) s2 = lWB + ((size_t)layer * 16 + (r - 64)) * 2048;
        else if (r < 96) s2 = lWC + ((size_t)layer * 16 + (r - 80)) * 2048;
        dst = wsml_bf + ((size_t)layer << 18) + (size_t)j * 4;
        if (s2) src = s2 + col;
    }
    ushort4 o;
    if (src) {
        float4 v = *(const float4*)src;
        o.x = f2bf(v.x); o.y = f2bf(v.y); o.z = f2bf(v.z); o.w = f2bf(v.w);
    } else { o.x = o.y = o.z = o.w = 0; }
    *(ushort4*)dst = o;
}

// ---------------- embedding + rmsnorm -> resid, xn_bf ----------------
__global__ void k_embed_norm(const int* __restrict__ ids, const float* __restrict__ emb,
                             const float* __restrict__ w, float* __restrict__ resid,
                             u16* __restrict__ out) {
    int tk = blockIdx.x, tid = threadIdx.x;
    int id = ids[tk];
    float4 v = *(const float4*)&emb[(size_t)id * Dd_ + tid * 4];
    *(float4*)&resid[(size_t)tk * Dd_ + tid * 4] = v;
    float ss = v.x * v.x + v.y * v.y + v.z * v.z + v.w * v.w;
    #pragma unroll
    for (int m = 32; m; m >>= 1) ss += __shfl_xor(ss, m);
    __shared__ float red[4];
    if ((tid & 63) == 0) red[tid >> 6] = ss;
    __syncthreads();
    ss = red[0] + red[1] + red[2] + red[3];
    float rs = rsqrtf(ss * (1.f / 1024.f) + 1e-5f);
    float4 wv = *(const float4*)&w[tid * 4];
    ushort4 o;
    o.x = f2bf(v.x * rs * wv.x); o.y = f2bf(v.y * rs * wv.y);
    o.z = f2bf(v.z * rs * wv.z); o.w = f2bf(v.w * rs * wv.w);
    *(ushort4*)&out[(size_t)tk * Dd_ + tid * 4] = o;
}

// ---------------- resid += p0+p1; xn_bf = rmsnorm(resid)*w ----------------
__global__ void k_add2_norm(const float* __restrict__ part, float* __restrict__ resid,
                            const float* __restrict__ w, u16* __restrict__ out) {
    int tk = blockIdx.x, tid = threadIdx.x;
    size_t i4 = (size_t)tk * Dd_ + tid * 4;
    float4 r = *(const float4*)&resid[i4];
    float4 a = *(const float4*)&part[i4];
    float4 b = *(const float4*)&part[(size_t)TOK * Dd_ + i4];
    r.x += a.x + b.x; r.y += a.y + b.y; r.z += a.z + b.z; r.w += a.w + b.w;
    *(float4*)&resid[i4] = r;
    float ss = r.x * r.x + r.y * r.y + r.z * r.z + r.w * r.w;
    #pragma unroll
    for (int m = 32; m; m >>= 1) ss += __shfl_xor(ss, m);
    __shared__ float red[4];
    if ((tid & 63) == 0) red[tid >> 6] = ss;
    __syncthreads();
    ss = red[0] + red[1] + red[2] + red[3];
    float rs = rsqrtf(ss * (1.f / 1024.f) + 1e-5f);
    float4 wv = *(const float4*)&w[tid * 4];
    ushort4 o;
    o.x = f2bf(r.x * rs * wv.x); o.y = f2bf(r.y * rs * wv.y);
    o.z = f2bf(r.z * rs * wv.z); o.w = f2bf(r.w * rs * wv.w);
    *(ushort4*)&out[(size_t)tk * Dd_ + tid * 4] = o;
}

// ---------------- depthwise causal conv + silu (reads xall+2048, ld=4096) ----------------
__global__ void k_conv_silu(const float* __restrict__ xin, const float* __restrict__ cw,
                            const float* __restrict__ cb, float* __restrict__ xout,
                            u16* __restrict__ xbf) {
    int blk = blockIdx.x;            // 4096 = TOK * 2
    int tk = blk >> 1;
    int e0 = ((blk & 1) << 10) + threadIdx.x * 4;
    int b = tk >> 10, l = tk & 1023;
    float4 w0 = *(const float4*)&cw[(size_t)(e0 + 0) * 4];
    float4 w1 = *(const float4*)&cw[(size_t)(e0 + 1) * 4];
    float4 w2 = *(const float4*)&cw[(size_t)(e0 + 2) * 4];
    float4 w3 = *(const float4*)&cw[(size_t)(e0 + 3) * 4];
    float4 bv = *(const float4*)&cb[e0];
    float a0 = bv.x, a1 = bv.y, a2 = bv.z, a3 = bv.w;
    const float* wp0 = (const float*)&w0; const float* wp1 = (const float*)&w1;
    const float* wp2 = (const float*)&w2; const float* wp3 = (const float*)&w3;
    #pragma unroll
    for (int k = 0; k < 4; ++k) {
        int ll = l - 3 + k;
        if (ll < 0) continue;
        float4 xv = *(const float4*)&xin[((size_t)(b * 1024 + ll)) * XLD + e0];
        a0 = fmaf(xv.x, wp0[k], a0); a1 = fmaf(xv.y, wp1[k], a1);
        a2 = fmaf(xv.z, wp2[k], a2); a3 = fmaf(xv.w, wp3[k], a3);
    }
    a0 = siluf(a0); a1 = siluf(a1); a2 = siluf(a2); a3 = siluf(a3);
    float4 o; o.x = a0; o.y = a1; o.z = a2; o.w = a3;
    *(float4*)&xout[(size_t)tk * Ed + e0] = o;
    ushort4 ob; ob.x = f2bf(a0); ob.y = f2bf(a1); ob.z = f2bf(a2); ob.w = f2bf(a3);
    *(ushort4*)&xbf[(size_t)tk * Ed + e0] = ob;
}

// ---------------- split-K reduce for xs (+ bf16 convert fused) ----------------
__global__ void k_reduce_xs(const float* __restrict__ part, float* __restrict__ xs,
                            u16* __restrict__ xsbf) {
    size_t i4 = ((size_t)blockIdx.x * 256 + threadIdx.x) * 4;   // over 2048*128
    float4 s = *(const float4*)&part[i4];
    #pragma unroll
    for (int c = 1; c < 8; ++c) {
        float4 v = *(const float4*)&part[(size_t)c * TOK * 128 + i4];
        s.x += v.x; s.y += v.y; s.z += v.z; s.w += v.w;
    }
    *(float4*)&xs[i4] = s;
    ushort4 o; o.x = f2bf(s.x); o.y = f2bf(s.y); o.z = f2bf(s.z); o.w = f2bf(s.w);
    *(ushort4*)&xsbf[i4] = o;
}

// ---------------- chunked scan (transposed: 1 thread per (c,b,e), n in regs) ----------------
__global__ void k_scan_pass1(const float* __restrict__ delta, const float* __restrict__ x,
                             const float* __restrict__ xs, const float* __restrict__ A_log,
                             float* __restrict__ sumd, float* __restrict__ Hc) {
    __shared__ float sBt[CLEN][16];
    int t = blockIdx.x * 256 + threadIdx.x;     // NCHUNK*B*E threads
    int e = t & (Ed - 1);
    int cb = t >> 11;                           // c*Bd + b
    int b = cb & 1, c = cb >> 1;
    int rowbase = b * 1024 + c * CLEN;
    {
        int f = threadIdx.x * 4;                // 1024 floats
        int row = f >> 4, cc = f & 15;
        float4 v = *(const float4*)&xs[(size_t)(rowbase + row) * 128 + 64 + cc];
        *(float4*)&sBt[row][cc] = v;
    }
    __syncthreads();
    float dA[16], h[16];
    #pragma unroll
    for (int n = 0; n < 16; ++n) { dA[n] = -__expf(A_log[e * 16 + n]); h[n] = 0.f; }
    float sd = 0.f;
    for (int l = 0; l < CLEN; ++l) {
        size_t row = (size_t)rowbase + l;
        float dlt = delta[row * Ed + e];
        float xv  = x[row * Ed + e];
        sd += dlt;
        float dx = dlt * xv;
        float4 bt0 = *(const float4*)&sBt[l][0];
        float4 bt1 = *(const float4*)&sBt[l][4];
        float4 bt2 = *(const float4*)&sBt[l][8];
        float4 bt3 = *(const float4*)&sBt[l][12];
        float bts[16] = {bt0.x,bt0.y,bt0.z,bt0.w, bt1.x,bt1.y,bt1.z,bt1.w,
                         bt2.x,bt2.y,bt2.z,bt2.w, bt3.x,bt3.y,bt3.z,bt3.w};
        #pragma unroll
        for (int n = 0; n < 16; ++n) {
            float a = __expf(dA[n] * dlt);
            h[n] = fmaf(a, h[n], dx * bts[n]);
        }
    }
    size_t gg = (size_t)cb * Ed + e;
    #pragma unroll
    for (int n = 0; n < 16; ++n) Hc[gg * 16 + n] = h[n];
    sumd[gg] = sd;
}

// pass2: computes its own chunk-prefix from sumd/Hc (combine fused in)
__global__ void k_scan_pass2(const float* __restrict__ delta, const float* __restrict__ x,
                             const float* __restrict__ xs, const float* __restrict__ A_log,
                             const float* __restrict__ sumd, const float* __restrict__ Hc,
                             const float* __restrict__ WD,
                             const float* __restrict__ skipg, u16* __restrict__ ybf) {
    __shared__ float sBC[CLEN][32];            // [:,0..15]=Bt, [:,16..31]=Ct
    int t = blockIdx.x * 256 + threadIdx.x;
    int e = t & (Ed - 1);
    int cb = t >> 11;
    int b = cb & 1, c = cb >> 1;
    int rowbase = b * 1024 + c * CLEN;
    {
        int f = threadIdx.x * 8;               // 2048 floats
        int row = f >> 5, cc = f & 31;
        float4 v0 = *(const float4*)&xs[(size_t)(rowbase + row) * 128 + 64 + cc];
        float4 v1 = *(const float4*)&xs[(size_t)(rowbase + row) * 128 + 64 + cc + 4];
        *(float4*)&sBC[row][cc] = v0;
        *(float4*)&sBC[row][cc + 4] = v1;
    }
    __syncthreads();
    float dA[16], h[16];
    #pragma unroll
    for (int n = 0; n < 16; ++n) {
        dA[n] = -__expf(A_log[e * 16 + n]);
        h[n] = 0.f;
    }
    // prefix over earlier chunks (fused combine)
    for (int cc = 0; cc < c; ++cc) {
        size_t g2 = ((size_t)(cc * Bd + b) * Ed + e);
        float sdc = sumd[g2];
        #pragma unroll
        for (int n = 0; n < 16; ++n)
            h[n] = fmaf(__expf(dA[n] * sdc), h[n], Hc[g2 * 16 + n]);
    }
    float wd = WD[e];
    for (int l = 0; l < CLEN; ++l) {
        size_t row = (size_t)rowbase + l;
        float dlt = delta[row * Ed + e];
        float xv  = x[row * Ed + e];
        float dx = dlt * xv;
        float4 b0 = *(const float4*)&sBC[l][0];
        float4 b1 = *(const float4*)&sBC[l][4];
        float4 b2 = *(const float4*)&sBC[l][8];
        float4 b3 = *(const float4*)&sBC[l][12];
        float4 c0 = *(const float4*)&sBC[l][16];
        float4 c1 = *(const float4*)&sBC[l][20];
        float4 c2 = *(const float4*)&sBC[l][24];
        float4 c3 = *(const float4*)&sBC[l][28];
        float bts[16] = {b0.x,b0.y,b0.z,b0.w, b1.x,b1.y,b1.z,b1.w,
                         b2.x,b2.y,b2.z,b2.w, b3.x,b3.y,b3.z,b3.w};
        float cts[16] = {c0.x,c0.y,c0.z,c0.w, c1.x,c1.y,c1.z,c1.w,
                         c2.x,c2.y,c2.z,c2.w, c3.x,c3.y,c3.z,c3.w};
        float y = 0.f;
        #pragma unroll
        for (int n = 0; n < 16; ++n) {
            float a = __expf(dA[n] * dlt);
            h[n] = fmaf(a, h[n], dx * bts[n]);
            y = fmaf(h[n], cts[n], y);
        }
        float yo = y + xv * wd;
        float sk = skipg[row * XLD + e];
        ybf[row * Ed + e] = f2bf(yo * siluf(sk));
    }
}

// ---------------- 128^2 bf16 MFMA GEMM (split-K capable) ----------------
// EPI: 0 = plain, 2 = softplus(v + aux[col])
template<int EPI>
__global__ __launch_bounds__(256, 2)
void k_gemm_bt(const u16* __restrict__ A, int lda,
               const u16* __restrict__ B, int ldb,
               float* __restrict__ C, int ldc,
               const float* __restrict__ aux,
               int ntm, int Nstore, int Kc, size_t Cz) {
    __shared__ u16 lsA[2][128 * 32];
    __shared__ u16 lsB[2][128 * 32];
    int kz = blockIdx.z;
    A += (size_t)kz * Kc;
    B += (size_t)kz * Kc;
    C += (size_t)kz * Cz;
    int tid = threadIdx.x;
    int bid = blockIdx.x;
    int mt = bid % ntm, nt = bid / ntm;
    int mBase = mt * 128, nBase = nt * 128;
    int lane = tid & 63, wid = tid >> 6;
    int wr = wid >> 1, wc = wid & 1;

    f32x4 acc[4][4] = {};
    const u16* Ablk = A + (size_t)mBase * lda;
    const u16* Bblk = B + (size_t)nBase * ldb;
    int nk = Kc >> 5;

    auto stage = [&](int buf, int kt) {
        #pragma unroll
        for (int i = 0; i < 2; ++i) {
            int chunk = i * 256 + tid;
            int row = chunk >> 2;
            int kc  = (chunk & 3) << 3;
            const u16* ga = Ablk + (size_t)row * lda + (kt << 5) + kc;
            const u16* gb = Bblk + (size_t)row * ldb + (kt << 5) + kc;
            u16* la = &lsA[buf][(size_t)(i * 256 + wid * 64) * 8];
            u16* lb = &lsB[buf][(size_t)(i * 256 + wid * 64) * 8];
            __builtin_amdgcn_global_load_lds((gvoid_t*)ga, (lvoid_t*)la, 16, 0, 0);
            __builtin_amdgcn_global_load_lds((gvoid_t*)gb, (lvoid_t*)lb, 16, 0, 0);
        }
    };
    auto compute = [&](int buf) {
        bf16x8 af[4], bfr[4];
        const u16* baseA = lsA[buf];
        const u16* baseB = lsB[buf];
        int kq = (lane >> 4) << 3;
        int r  = lane & 15;
        #pragma unroll
        for (int mi = 0; mi < 4; ++mi)
            af[mi] = *(const bf16x8*)&baseA[(size_t)((wr * 64 + mi * 16 + r) * 32 + kq)];
        #pragma unroll
        for (int ni = 0; ni < 4; ++ni)
            bfr[ni] = *(const bf16x8*)&baseB[(size_t)((wc * 64 + ni * 16 + r) * 32 + kq)];
        #pragma unroll
        for (int mi = 0; mi < 4; ++mi)
            #pragma unroll
            for (int ni = 0; ni < 4; ++ni)
                acc[mi][ni] = __builtin_amdgcn_mfma_f32_16x16x32_bf16(af[mi], bfr[ni], acc[mi][ni], 0, 0, 0);
    };

    stage(0, 0);
    asm volatile("s_waitcnt vmcnt(0)" ::: "memory");
    __syncthreads();
    int cur = 0;
    for (int kt = 0; kt + 1 < nk; ++kt) {
        stage(cur ^ 1, kt + 1);
        compute(cur);
        asm volatile("s_waitcnt vmcnt(0)" ::: "memory");
        __syncthreads();
        cur ^= 1;
    }
    compute(cur);

    int rbase = (lane >> 4) * 4, ccol = lane & 15;
    #pragma unroll
    for (int mi = 0; mi < 4; ++mi) {
        #pragma unroll
        for (int ni = 0; ni < 4; ++ni) {
            int gc = nBase + wc * 64 + ni * 16 + ccol;
            if (gc < Nstore) {
                float bias = (EPI == 2) ? aux[gc] : 0.f;
                #pragma unroll
                for (int rr = 0; rr < 4; ++rr) {
                    int gr = mBase + wr * 64 + mi * 16 + rbase + rr;
                    size_t off = (size_t)gr * ldc + gc;
                    float v = acc[mi][ni][rr];
                    if (EPI == 2) v = softplusf(v + bias);
                    C[off] = v;
                }
            }
        }
    }
}

// ---------------- 256^2 8-phase bf16 GEMM (lm_head) ----------------
// R2 schedule + pre-barrier frag ds_reads (phases 1-3, 5-7). No asm lgkm waits:
// compiler tracks the frag->MFMA dependency itself.
#define BAR()    asm volatile("s_barrier" ::: "memory")
#define WAITV2() asm volatile("s_waitcnt vmcnt(2)" ::: "memory")
#define WAITV0() asm volatile("s_waitcnt vmcnt(0)" ::: "memory")

#define STG(buf, mat, h, kt) { \
    const u16* _s0 = ((mat) ? srcB[(h)*2]     : srcA[(h)*2])     + (size_t)(kt) * 64; \
    const u16* _s1 = ((mat) ? srcB[(h)*2 + 1] : srcA[(h)*2 + 1]) + (size_t)(kt) * 64; \
    char* _d = (char*)&ls[buf][mat][0]; \
    __builtin_amdgcn_global_load_lds((gvoid_t*)_s0, (lvoid_t*)(_d + (h)*16384 + tid*16), 16, 0, 0); \
    __builtin_amdgcn_global_load_lds((gvoid_t*)_s1, (lvoid_t*)(_d + (h)*16384 + 8192 + tid*16), 16, 0, 0); }

#define LDFRAG(buf, kk, mih) { \
    const char* _pa = (const char*)&ls[buf][0][0]; \
    const char* _pb = (const char*)&ls[buf][1][0]; \
    _Pragma("unroll") \
    for (int _m = 0; _m < 4; ++_m) \
        af[_m] = *(const bf16x8*)(_pa + abase + ((mih)*4 + _m) * 2048 + (kk) * 1024); \
    _Pragma("unroll") \
    for (int _n = 0; _n < 4; ++_n) \
        bfr[_n] = *(const bf16x8*)(_pb + bbase + _n * 2048 + (kk) * 1024); }

#define MMONLY(mih) { \
    __builtin_amdgcn_s_setprio(1); \
    _Pragma("unroll") \
    for (int _m = 0; _m < 4; ++_m) \
        _Pragma("unroll") \
        for (int _n = 0; _n < 4; ++_n) \
            acc[(mih)*4 + _m][_n] = __builtin_amdgcn_mfma_f32_16x16x32_bf16(af[_m], bfr[_n], acc[(mih)*4 + _m][_n], 0, 0, 0); \
    __builtin_amdgcn_s_setprio(0); }

__global__ __launch_bounds__(512, 2)
void k_gemm256(const u16* __restrict__ A, int lda,
               const u16* __restrict__ B, int ldb,
               float* __restrict__ C, int ldc,
               int ntm, int Nstore, int K) {
    __shared__ u16 ls[2][2][256 * 64];     // 128 KiB
    const int tid = threadIdx.x;
    const int lane = tid & 63, wid = tid >> 6;
    const int wr = wid >> 2, wc = wid & 3;

    // bijective XCD swizzle
    int nwg = gridDim.x, bid = blockIdx.x;
    int q8 = nwg >> 3, r8 = nwg & 7;
    int xcd = bid & 7, linb = bid >> 3;
    int sb = (xcd < r8 ? xcd * (q8 + 1) : r8 * (q8 + 1) + (xcd - r8) * q8) + linb;
    int mt = sb % ntm, nt = sb / ntm;

    const u16* Ablk = A + (size_t)(mt * 256) * lda;
    const u16* Bblk = B + (size_t)(nt * 256) * ldb;

    // staging sources: dest byte p = s*8192 + tid*16 (linear); logical = unswizzle(p)
    const u16* srcA[4]; const u16* srcB[4];
    #pragma unroll
    for (int s = 0; s < 4; ++s) {
        int p = s * 8192 + tid * 16;
        int qq = p ^ (((p >> 9) & 1) << 5);
        int sub = qq >> 10, rin = (qq >> 6) & 15, cby = qq & 63;
        int row = ((sub >> 1) << 4) | rin;
        int col = ((((sub & 1) << 6) | cby)) >> 1;
        srcA[s] = Ablk + (size_t)row * lda + col;
        srcB[s] = Bblk + (size_t)row * ldb + col;
    }
    // read-side swizzled base offsets (mi adds 2048B, kk adds 1024B)
    int l15 = lane & 15;
    int lowb = (l15 * 64 + ((lane >> 4) << 4)) ^ (((l15 >> 3) & 1) << 5);
    int abase = wr * 16384 + lowb;
    int bbase = wc * 8192  + lowb;

    f32x4 acc[8][4] = {};
    bf16x8 af[4], bfr[4];
    int nk = K >> 6, nit = nk >> 1;

    // prologue: tile 0 -> buf0 (8 loads)
    STG(0, 0, 0, 0); STG(0, 0, 1, 0); STG(0, 1, 0, 0); STG(0, 1, 1, 0);

    for (int i = 0; i < nit; ++i) {
        int t1 = 2 * i + 1, t2 = 2 * i + 2;
        bool more = (i + 1 < nit);
        // ph0 (buf0 validated only at this barrier -> read after)
        STG(1, 0, 0, t1);
        WAITV2(); BAR();
        LDFRAG(0, 0, 0); MMONLY(0); BAR();
        // ph1 (buf0 valid -> hoist reads pre-barrier)
        LDFRAG(0, 0, 1);
        STG(1, 0, 1, t1);
        BAR();
        MMONLY(1); BAR();
        // ph2
        LDFRAG(0, 1, 0);
        STG(1, 1, 0, t1);
        BAR();
        MMONLY(0); BAR();
        // ph3
        LDFRAG(0, 1, 1);
        STG(1, 1, 1, t1);
        BAR();
        MMONLY(1); BAR();
        // ph4 (buf1 validated only at this barrier -> read after)
        if (more) { STG(0, 0, 0, t2); WAITV2(); } else { WAITV0(); }
        BAR();
        LDFRAG(1, 0, 0); MMONLY(0); BAR();
        // ph5
        LDFRAG(1, 0, 1);
        if (more) STG(0, 0, 1, t2);
        BAR();
        MMONLY(1); BAR();
        // ph6
        LDFRAG(1, 1, 0);
        if (more) STG(0, 1, 0, t2);
        BAR();
        MMONLY(0); BAR();
        // ph7
        LDFRAG(1, 1, 1);
        if (more) STG(0, 1, 1, t2);
        BAR();
        MMONLY(1); BAR();
    }

    int rb = (lane >> 4) * 4, cc = lane & 15;
    int mrow = mt * 256 + wr * 128, ncol = nt * 256 + wc * 64;
    #pragma unroll
    for (int mi = 0; mi < 8; ++mi) {
        #pragma unroll
        for (int ni = 0; ni < 4; ++ni) {
            int gc = ncol + ni * 16 + cc;
            if (gc < Nstore) {
                #pragma unroll
                for (int rr = 0; rr < 4; ++rr) {
                    size_t off = (size_t)(mrow + mi * 16 + rb + rr) * ldc + gc;
                    C[off] = acc[mi][ni][rr];
                }
            }
        }
    }
}

// ---------------- launch ----------------
extern "C" void kernel_launch(void* const* d_in, const int* in_sizes, int n_in,
                              void* d_out, int out_size, void* d_ws, size_t ws_size,
                              hipStream_t stream) {
    const int*   ids   = (const int*)d_in[0];
    const float* emb   = (const float*)d_in[1];
    const float* lmw   = (const float*)d_in[2];
    const float* normw = (const float*)d_in[3];
    const float* lnw   = (const float*)d_in[4];
    const float* lskip = (const float*)d_in[5];
    const float* linw  = (const float*)d_in[6];
    const float* lcw   = (const float*)d_in[7];
    const float* lcb   = (const float*)d_in[8];
    const float* lWd1  = (const float*)d_in[9];
    const float* lWd2  = (const float*)d_in[10];
    const float* lWd2b = (const float*)d_in[11];
    const float* lWB   = (const float*)d_in[12];
    const float* lWC   = (const float*)d_in[13];
    const float* lAlog = (const float*)d_in[14];
    const float* lWD   = (const float*)d_in[15];
    const float* loutw = (const float*)d_in[16];
    float* out = (float*)d_out;

    char* ws = (char*)d_ws;
    size_t off = 0;
    auto alloc = [&](size_t bytes) { char* p = ws + off; off += (bytes + 255) & ~(size_t)255; return p; };
    u16*   lm_bf    = (u16*)  alloc((size_t)VPAD * 1024 * 2);
    u16*   wsi_bf   = (u16*)  alloc((size_t)NL * 4096 * Dd_ * 2);   // [skip;in] concat
    u16*   wout_bf  = (u16*)  alloc((size_t)NL * Dd_ * Ed * 2);
    u16*   wd2_bf   = (u16*)  alloc((size_t)NL * Ed * 64 * 2);
    u16*   wsml_bf  = (u16*)  alloc((size_t)NL * 128 * Ed * 2);
    float* resid    = (float*)alloc((size_t)TOK * Dd_ * 4);
    u16*   xn_bf    = (u16*)  alloc((size_t)TOK * Dd_ * 2);
    float* xall     = (float*)alloc((size_t)TOK * XLD * 4);         // cols 0-2047 skip, 2048-4095 xin
    float* xf       = (float*)alloc((size_t)TOK * Ed * 4);
    u16*   xbf      = (u16*)  alloc((size_t)TOK * Ed * 2);
    float* xs       = (float*)alloc((size_t)TOK * 128 * 4);
    u16*   xs_bf    = (u16*)  alloc((size_t)TOK * 128 * 2);
    float* xs_part  = (float*)alloc((size_t)8 * TOK * 128 * 4);
    float* opart    = (float*)alloc((size_t)2 * TOK * Dd_ * 4);
    float* delta    = (float*)alloc((size_t)TOK * Ed * 4);
    float* sumd     = (float*)alloc((size_t)NCHUNK * Bd * Ed * 4);
    float* Hc       = (float*)alloc((size_t)NCHUNK * Bd * Ed * Nd * 4);
    u16*   ybf      = (u16*)  alloc((size_t)TOK * Ed * 2);
    (void)ws_size; (void)in_sizes; (void)n_in; (void)out_size;

    // all weight conversions in one dispatch
    k_convert_all<<<63488, 256, 0, stream>>>(lmw, lskip, linw, loutw, lWd2, lWd1, lWB, lWC,
                                             lm_bf, wsi_bf, wout_bf, wd2_bf, wsml_bf);

    // embedding + layer-0 norm
    k_embed_norm<<<TOK, 256, 0, stream>>>(ids, emb, lnw, resid, xn_bf);

    for (int lyr = 0; lyr < NL; ++lyr) {
        const float* Alog = lAlog + (size_t)lyr * Ed * Nd;
        // [skip | xin] = xn @ [skip_w; in_w]^T   (M=2048, N=4096, K=1024)
        k_gemm_bt<0><<<dim3(16 * 32, 1, 1), 256, 0, stream>>>(xn_bf, Dd_,
            wsi_bf + (size_t)lyr * 4096 * Dd_, Dd_, xall, XLD, nullptr, 16, 4096, 1024, 0);
        k_conv_silu<<<TOK * 2, 256, 0, stream>>>(xall + Ed, lcw + (size_t)lyr * Ed * 4,
                                                 lcb + (size_t)lyr * Ed, xf, xbf);
        // xs_part[c] = x @ [Wd1;WB;WC]^T  split-K (8 chunks of 256)
        k_gemm_bt<0><<<dim3(16, 1, 8), 256, 0, stream>>>(xbf, Ed,
            wsml_bf + (size_t)lyr * 128 * Ed, Ed, xs_part, 128, nullptr, 16, 128, 256,
            (size_t)TOK * 128);
        k_reduce_xs<<<TOK * 128 / 4 / 256, 256, 0, stream>>>(xs_part, xs, xs_bf);
        // delta = softplus(xd @ Wd2^T + b)  (epilogue-fused)
        k_gemm_bt<2><<<dim3(16 * 16, 1, 1), 256, 0, stream>>>(xs_bf, 128,
            wd2_bf + (size_t)lyr * Ed * 64, 64, delta, Ed, lWd2b + (size_t)lyr * Ed,
            16, Ed, 64, 0);
        // chunked scan (transposed; combine fused into pass2)
        k_scan_pass1<<<NCHUNK * Bd * Ed / 256, 256, 0, stream>>>(delta, xf, xs, Alog, sumd, Hc);
        k_scan_pass2<<<NCHUNK * Bd * Ed / 256, 256, 0, stream>>>(delta, xf, xs, Alog,
            sumd, Hc, lWD + (size_t)lyr * Ed, xall, ybf);
        // opart[z] = y @ out_w^T (split-K z=2), then resid += p0+p1 and next norm
        k_gemm_bt<0><<<dim3(16 * 8, 1, 2), 256, 0, stream>>>(ybf, Ed,
            wout_bf + (size_t)lyr * Dd_ * Ed, Ed, opart, Dd_, nullptr, 16, Dd_, 1024,
            (size_t)TOK * Dd_);
        const float* nw = (lyr == NL - 1) ? normw : lnw + (size_t)(lyr + 1) * Dd_;
        k_add2_norm<<<TOK, 256, 0, stream>>>(opart, resid, nw, xn_bf);
    }

    // lm_head (256^2 8-phase)
    k_gemm256<<<dim3(8 * (VPAD / 256), 1, 1), 512, 0, stream>>>(xn_bf, Dd_, lm_bf, Dd_,
        out, VREAL, 8, VREAL, 1024);
}

// Round 8
// 784.614 us; speedup vs baseline: 1.0251x; 1.0251x over previous
//
#include <hip/hip_runtime.h>

typedef unsigned short u16;
using bf16x8 = __attribute__((ext_vector_type(8))) __bf16;
using f32x4  = __attribute__((ext_vector_type(4))) float;

typedef const void __attribute__((address_space(1))) gvoid_t;
typedef void __attribute__((address_space(3))) lvoid_t;

#define NL 2
#define Bd 2
#define Ld 1024
#define Dd_ 1024
#define Ed 2048
#define Nd 16
#define TOK (Bd*Ld)          // 2048 tokens
#define VPAD 50432           // 197 * 256
#define VREAL 50280
#define NCHUNK 16
#define CLEN 64
#define XLD 4096             // combined skip|xin row stride

__device__ __forceinline__ u16 f2bf(float f) {
    union { float f; unsigned u; } v; v.f = f;
    unsigned u = v.u;
    unsigned r = (u + 0x7fffu + ((u >> 16) & 1u)) >> 16;
    return (u16)r;
}
__device__ __forceinline__ float bf2f(u16 u) {
    union { unsigned u; float f; } v; v.u = ((unsigned)u) << 16; return v.f;
}
__device__ __forceinline__ unsigned pk2(float a, float b) {
    return (unsigned)f2bf(a) | ((unsigned)f2bf(b) << 16);
}
__device__ __forceinline__ float siluf(float x) { return x / (1.f + __expf(-x)); }
__device__ __forceinline__ float softplusf(float z) {
    return (z > 15.f) ? z : log1pf(__expf(z));
}

// ---------------- one-shot weight conversion (8 floats/thread, 16B stores) ----------------
// granule = 8 floats. Regions (granule index):
//   [0, 6455296)           lm_head pad to VPAD rows (valid < 6435840)
//   [6455296, 7503872)     wsi concat [skip;in] per layer
//   [7503872, 8028160)     wout
//   [8028160, 8060928)     wd2
//   [8060928, 8126464)     wsmall pack [Wd1;WB;WC;0]
__global__ void k_convert_all(const float* __restrict__ lmw, const float* __restrict__ lskip,
                              const float* __restrict__ linw, const float* __restrict__ loutw,
                              const float* __restrict__ lWd2, const float* __restrict__ lWd1,
                              const float* __restrict__ lWB, const float* __restrict__ lWC,
                              u16* __restrict__ lm_bf, u16* __restrict__ wsi_bf,
                              u16* __restrict__ wout_bf, u16* __restrict__ wd2_bf,
                              u16* __restrict__ wsml_bf) {
    int g = blockIdx.x * 256 + threadIdx.x;
    const float* src = nullptr; u16* dst = nullptr;
    if (g < 6455296) {
        dst = lm_bf + (size_t)g * 8;
        if (g < 6435840) src = lmw + (size_t)g * 8;
    } else if (g < 7503872) {
        int i = g - 6455296;
        int layer = i >> 19;
        int within = i & 524287;
        int mat = within >> 18;
        int idx = within & 262143;
        src = (mat ? linw : lskip) + ((size_t)layer << 21) + ((size_t)idx * 8);
        dst = wsi_bf + ((size_t)layer << 22) + ((size_t)mat << 21) + ((size_t)idx * 8);
    } else if (g < 8028160) {
        int i = g - 7503872;
        src = loutw + (size_t)i * 8; dst = wout_bf + (size_t)i * 8;
    } else if (g < 8060928) {
        int i = g - 8028160;
        src = lWd2 + (size_t)i * 8; dst = wd2_bf + (size_t)i * 8;
    } else {
        int i = g - 8060928;
        int layer = i >> 15;
        int j = i & 32767;
        int col = (j * 8) & 2047;
        int r = (j * 8) >> 11;
        const float* s2 = nullptr;
        if (r < 64) s2 = lWd1 + ((size_t)layer * 64 + r) * 2048;
        else if (r < 80) s2 = lWB + ((size_t)layer * 16 + (r - 64)) * 2048;
        else if (r < 96) s2 = lWC + ((size_t)layer * 16 + (r - 80)) * 2048;
        dst = wsml_bf + ((size_t)layer << 18) + (size_t)j * 8;
        if (s2) src = s2 + col;
    }
    uint4 o;
    if (src) {
        float4 v0 = *(const float4*)src;
        float4 v1 = *(const float4*)(src + 4);
        o.x = pk2(v0.x, v0.y); o.y = pk2(v0.z, v0.w);
        o.z = pk2(v1.x, v1.y); o.w = pk2(v1.z, v1.w);
    } else { o.x = o.y = o.z = o.w = 0; }
    *(uint4*)dst = o;
}

// ---------------- embedding + rmsnorm -> resid, xn_bf ----------------
__global__ void k_embed_norm(const int* __restrict__ ids, const float* __restrict__ emb,
                             const float* __restrict__ w, float* __restrict__ resid,
                             u16* __restrict__ out) {
    int tk = blockIdx.x, tid = threadIdx.x;
    int id = ids[tk];
    float4 v = *(const float4*)&emb[(size_t)id * Dd_ + tid * 4];
    *(float4*)&resid[(size_t)tk * Dd_ + tid * 4] = v;
    float ss = v.x * v.x + v.y * v.y + v.z * v.z + v.w * v.w;
    #pragma unroll
    for (int m = 32; m; m >>= 1) ss += __shfl_xor(ss, m);
    __shared__ float red[4];
    if ((tid & 63) == 0) red[tid >> 6] = ss;
    __syncthreads();
    ss = red[0] + red[1] + red[2] + red[3];
    float rs = rsqrtf(ss * (1.f / 1024.f) + 1e-5f);
    float4 wv = *(const float4*)&w[tid * 4];
    ushort4 o;
    o.x = f2bf(v.x * rs * wv.x); o.y = f2bf(v.y * rs * wv.y);
    o.z = f2bf(v.z * rs * wv.z); o.w = f2bf(v.w * rs * wv.w);
    *(ushort4*)&out[(size_t)tk * Dd_ + tid * 4] = o;
}

// ---------------- resid += p0+p1; xn_bf = rmsnorm(resid)*w ----------------
__global__ void k_add2_norm(const float* __restrict__ part, float* __restrict__ resid,
                            const float* __restrict__ w, u16* __restrict__ out) {
    int tk = blockIdx.x, tid = threadIdx.x;
    size_t i4 = (size_t)tk * Dd_ + tid * 4;
    float4 r = *(const float4*)&resid[i4];
    float4 a = *(const float4*)&part[i4];
    float4 b = *(const float4*)&part[(size_t)TOK * Dd_ + i4];
    r.x += a.x + b.x; r.y += a.y + b.y; r.z += a.z + b.z; r.w += a.w + b.w;
    *(float4*)&resid[i4] = r;
    float ss = r.x * r.x + r.y * r.y + r.z * r.z + r.w * r.w;
    #pragma unroll
    for (int m = 32; m; m >>= 1) ss += __shfl_xor(ss, m);
    __shared__ float red[4];
    if ((tid & 63) == 0) red[tid >> 6] = ss;
    __syncthreads();
    ss = red[0] + red[1] + red[2] + red[3];
    float rs = rsqrtf(ss * (1.f / 1024.f) + 1e-5f);
    float4 wv = *(const float4*)&w[tid * 4];
    ushort4 o;
    o.x = f2bf(r.x * rs * wv.x); o.y = f2bf(r.y * rs * wv.y);
    o.z = f2bf(r.z * rs * wv.z); o.w = f2bf(r.w * rs * wv.w);
    *(ushort4*)&out[(size_t)tk * Dd_ + tid * 4] = o;
}

// ---------------- depthwise causal conv + silu (bf16 in, bf16 out) ----------------
__global__ void k_conv_silu(const u16* __restrict__ xin, const float* __restrict__ cw,
                            const float* __restrict__ cb, u16* __restrict__ xbf) {
    int blk = blockIdx.x;            // 4096 = TOK * 2
    int tk = blk >> 1;
    int e0 = ((blk & 1) << 10) + threadIdx.x * 4;
    int b = tk >> 10, l = tk & 1023;
    float4 w0 = *(const float4*)&cw[(size_t)(e0 + 0) * 4];
    float4 w1 = *(const float4*)&cw[(size_t)(e0 + 1) * 4];
    float4 w2 = *(const float4*)&cw[(size_t)(e0 + 2) * 4];
    float4 w3 = *(const float4*)&cw[(size_t)(e0 + 3) * 4];
    float4 bv = *(const float4*)&cb[e0];
    float a0 = bv.x, a1 = bv.y, a2 = bv.z, a3 = bv.w;
    const float* wp0 = (const float*)&w0; const float* wp1 = (const float*)&w1;
    const float* wp2 = (const float*)&w2; const float* wp3 = (const float*)&w3;
    #pragma unroll
    for (int k = 0; k < 4; ++k) {
        int ll = l - 3 + k;
        if (ll < 0) continue;
        ushort4 xv = *(const ushort4*)&xin[((size_t)(b * 1024 + ll)) * XLD + e0];
        a0 = fmaf(bf2f(xv.x), wp0[k], a0); a1 = fmaf(bf2f(xv.y), wp1[k], a1);
        a2 = fmaf(bf2f(xv.z), wp2[k], a2); a3 = fmaf(bf2f(xv.w), wp3[k], a3);
    }
    a0 = siluf(a0); a1 = siluf(a1); a2 = siluf(a2); a3 = siluf(a3);
    ushort4 ob; ob.x = f2bf(a0); ob.y = f2bf(a1); ob.z = f2bf(a2); ob.w = f2bf(a3);
    *(ushort4*)&xbf[(size_t)tk * Ed + e0] = ob;
}

// ---------------- split-K reduce for xs (+ bf16 convert fused) ----------------
__global__ void k_reduce_xs(const float* __restrict__ part, float* __restrict__ xs,
                            u16* __restrict__ xsbf) {
    size_t i4 = ((size_t)blockIdx.x * 256 + threadIdx.x) * 4;   // over 2048*128
    float4 s = *(const float4*)&part[i4];
    #pragma unroll
    for (int c = 1; c < 8; ++c) {
        float4 v = *(const float4*)&part[(size_t)c * TOK * 128 + i4];
        s.x += v.x; s.y += v.y; s.z += v.z; s.w += v.w;
    }
    *(float4*)&xs[i4] = s;
    ushort4 o; o.x = f2bf(s.x); o.y = f2bf(s.y); o.z = f2bf(s.z); o.w = f2bf(s.w);
    *(ushort4*)&xsbf[i4] = o;
}

// ---------------- chunked scan (transposed: 1 thread per (c,b,e), n in regs) ----------------
__global__ void k_scan_pass1(const float* __restrict__ delta, const u16* __restrict__ x,
                             const float* __restrict__ xs, const float* __restrict__ A_log,
                             float* __restrict__ sumd, float* __restrict__ Hc) {
    __shared__ float sBt[CLEN][16];
    int t = blockIdx.x * 256 + threadIdx.x;     // NCHUNK*B*E threads
    int e = t & (Ed - 1);
    int cb = t >> 11;                           // c*Bd + b
    int b = cb & 1, c = cb >> 1;
    int rowbase = b * 1024 + c * CLEN;
    {
        int f = threadIdx.x * 4;                // 1024 floats
        int row = f >> 4, cc = f & 15;
        float4 v = *(const float4*)&xs[(size_t)(rowbase + row) * 128 + 64 + cc];
        *(float4*)&sBt[row][cc] = v;
    }
    __syncthreads();
    float dA[16], h[16];
    #pragma unroll
    for (int n = 0; n < 16; ++n) { dA[n] = -__expf(A_log[e * 16 + n]); h[n] = 0.f; }
    float sd = 0.f;
    for (int l = 0; l < CLEN; ++l) {
        size_t row = (size_t)rowbase + l;
        float dlt = delta[row * Ed + e];
        float xv  = bf2f(x[row * Ed + e]);
        sd += dlt;
        float dx = dlt * xv;
        float4 bt0 = *(const float4*)&sBt[l][0];
        float4 bt1 = *(const float4*)&sBt[l][4];
        float4 bt2 = *(const float4*)&sBt[l][8];
        float4 bt3 = *(const float4*)&sBt[l][12];
        float bts[16] = {bt0.x,bt0.y,bt0.z,bt0.w, bt1.x,bt1.y,bt1.z,bt1.w,
                         bt2.x,bt2.y,bt2.z,bt2.w, bt3.x,bt3.y,bt3.z,bt3.w};
        #pragma unroll
        for (int n = 0; n < 16; ++n) {
            float a = __expf(dA[n] * dlt);
            h[n] = fmaf(a, h[n], dx * bts[n]);
        }
    }
    size_t gg = (size_t)cb * Ed + e;
    #pragma unroll
    for (int n = 0; n < 16; ++n) Hc[gg * 16 + n] = h[n];
    sumd[gg] = sd;
}

// pass2: computes its own chunk-prefix from sumd/Hc (combine fused in)
__global__ void k_scan_pass2(const float* __restrict__ delta, const u16* __restrict__ x,
                             const float* __restrict__ xs, const float* __restrict__ A_log,
                             const float* __restrict__ sumd, const float* __restrict__ Hc,
                             const float* __restrict__ WD,
                             const u16* __restrict__ skipg, u16* __restrict__ ybf) {
    __shared__ float sBC[CLEN][32];            // [:,0..15]=Bt, [:,16..31]=Ct
    int t = blockIdx.x * 256 + threadIdx.x;
    int e = t & (Ed - 1);
    int cb = t >> 11;
    int b = cb & 1, c = cb >> 1;
    int rowbase = b * 1024 + c * CLEN;
    {
        int f = threadIdx.x * 8;               // 2048 floats
        int row = f >> 5, cc = f & 31;
        float4 v0 = *(const float4*)&xs[(size_t)(rowbase + row) * 128 + 64 + cc];
        float4 v1 = *(const float4*)&xs[(size_t)(rowbase + row) * 128 + 64 + cc + 4];
        *(float4*)&sBC[row][cc] = v0;
        *(float4*)&sBC[row][cc + 4] = v1;
    }
    __syncthreads();
    float dA[16], h[16];
    #pragma unroll
    for (int n = 0; n < 16; ++n) {
        dA[n] = -__expf(A_log[e * 16 + n]);
        h[n] = 0.f;
    }
    // prefix over earlier chunks (fused combine)
    for (int cc = 0; cc < c; ++cc) {
        size_t g2 = ((size_t)(cc * Bd + b) * Ed + e);
        float sdc = sumd[g2];
        #pragma unroll
        for (int n = 0; n < 16; ++n)
            h[n] = fmaf(__expf(dA[n] * sdc), h[n], Hc[g2 * 16 + n]);
    }
    float wd = WD[e];
    for (int l = 0; l < CLEN; ++l) {
        size_t row = (size_t)rowbase + l;
        float dlt = delta[row * Ed + e];
        float xv  = bf2f(x[row * Ed + e]);
        float dx = dlt * xv;
        float4 b0 = *(const float4*)&sBC[l][0];
        float4 b1 = *(const float4*)&sBC[l][4];
        float4 b2 = *(const float4*)&sBC[l][8];
        float4 b3 = *(const float4*)&sBC[l][12];
        float4 c0 = *(const float4*)&sBC[l][16];
        float4 c1 = *(const float4*)&sBC[l][20];
        float4 c2 = *(const float4*)&sBC[l][24];
        float4 c3 = *(const float4*)&sBC[l][28];
        float bts[16] = {b0.x,b0.y,b0.z,b0.w, b1.x,b1.y,b1.z,b1.w,
                         b2.x,b2.y,b2.z,b2.w, b3.x,b3.y,b3.z,b3.w};
        float cts[16] = {c0.x,c0.y,c0.z,c0.w, c1.x,c1.y,c1.z,c1.w,
                         c2.x,c2.y,c2.z,c2.w, c3.x,c3.y,c3.z,c3.w};
        float y = 0.f;
        #pragma unroll
        for (int n = 0; n < 16; ++n) {
            float a = __expf(dA[n] * dlt);
            h[n] = fmaf(a, h[n], dx * bts[n]);
            y = fmaf(h[n], cts[n], y);
        }
        float yo = y + xv * wd;
        float sk = bf2f(skipg[row * XLD + e]);
        ybf[row * Ed + e] = f2bf(yo * siluf(sk));
    }
}

// ---------------- 128^2 bf16 MFMA GEMM (split-K capable) ----------------
// EPI: 0 = plain f32, 2 = softplus(v + aux[col]) f32, 3 = bf16 store
template<int EPI>
__global__ __launch_bounds__(256, 2)
void k_gemm_bt(const u16* __restrict__ A, int lda,
               const u16* __restrict__ B, int ldb,
               float* __restrict__ C, int ldc,
               const float* __restrict__ aux,
               int ntm, int Nstore, int Kc, size_t Cz) {
    __shared__ u16 lsA[2][128 * 32];
    __shared__ u16 lsB[2][128 * 32];
    int kz = blockIdx.z;
    A += (size_t)kz * Kc;
    B += (size_t)kz * Kc;
    C += (size_t)kz * Cz;
    int tid = threadIdx.x;
    int bid = blockIdx.x;
    int mt = bid % ntm, nt = bid / ntm;
    int mBase = mt * 128, nBase = nt * 128;
    int lane = tid & 63, wid = tid >> 6;
    int wr = wid >> 1, wc = wid & 1;

    f32x4 acc[4][4] = {};
    const u16* Ablk = A + (size_t)mBase * lda;
    const u16* Bblk = B + (size_t)nBase * ldb;
    int nk = Kc >> 5;

    auto stage = [&](int buf, int kt) {
        #pragma unroll
        for (int i = 0; i < 2; ++i) {
            int chunk = i * 256 + tid;
            int row = chunk >> 2;
            int kc  = (chunk & 3) << 3;
            const u16* ga = Ablk + (size_t)row * lda + (kt << 5) + kc;
            const u16* gb = Bblk + (size_t)row * ldb + (kt << 5) + kc;
            u16* la = &lsA[buf][(size_t)(i * 256 + wid * 64) * 8];
            u16* lb = &lsB[buf][(size_t)(i * 256 + wid * 64) * 8];
            __builtin_amdgcn_global_load_lds((gvoid_t*)ga, (lvoid_t*)la, 16, 0, 0);
            __builtin_amdgcn_global_load_lds((gvoid_t*)gb, (lvoid_t*)lb, 16, 0, 0);
        }
    };
    auto compute = [&](int buf) {
        bf16x8 af[4], bfr[4];
        const u16* baseA = lsA[buf];
        const u16* baseB = lsB[buf];
        int kq = (lane >> 4) << 3;
        int r  = lane & 15;
        #pragma unroll
        for (int mi = 0; mi < 4; ++mi)
            af[mi] = *(const bf16x8*)&baseA[(size_t)((wr * 64 + mi * 16 + r) * 32 + kq)];
        #pragma unroll
        for (int ni = 0; ni < 4; ++ni)
            bfr[ni] = *(const bf16x8*)&baseB[(size_t)((wc * 64 + ni * 16 + r) * 32 + kq)];
        #pragma unroll
        for (int mi = 0; mi < 4; ++mi)
            #pragma unroll
            for (int ni = 0; ni < 4; ++ni)
                acc[mi][ni] = __builtin_amdgcn_mfma_f32_16x16x32_bf16(af[mi], bfr[ni], acc[mi][ni], 0, 0, 0);
    };

    stage(0, 0);
    asm volatile("s_waitcnt vmcnt(0)" ::: "memory");
    __syncthreads();
    int cur = 0;
    for (int kt = 0; kt + 1 < nk; ++kt) {
        stage(cur ^ 1, kt + 1);
        compute(cur);
        asm volatile("s_waitcnt vmcnt(0)" ::: "memory");
        __syncthreads();
        cur ^= 1;
    }
    compute(cur);

    int rbase = (lane >> 4) * 4, ccol = lane & 15;
    #pragma unroll
    for (int mi = 0; mi < 4; ++mi) {
        #pragma unroll
        for (int ni = 0; ni < 4; ++ni) {
            int gc = nBase + wc * 64 + ni * 16 + ccol;
            if (gc < Nstore) {
                float bias = (EPI == 2) ? aux[gc] : 0.f;
                #pragma unroll
                for (int rr = 0; rr < 4; ++rr) {
                    int gr = mBase + wr * 64 + mi * 16 + rbase + rr;
                    size_t off = (size_t)gr * ldc + gc;
                    float v = acc[mi][ni][rr];
                    if (EPI == 2) v = softplusf(v + bias);
                    if (EPI == 3) ((u16*)C)[off] = f2bf(v);
                    else          C[off] = v;
                }
            }
        }
    }
}

// ---------------- 256^2 8-phase bf16 GEMM (lm_head) — frozen ----------------
#define BAR()    asm volatile("s_barrier" ::: "memory")
#define WAITV2() asm volatile("s_waitcnt vmcnt(2)" ::: "memory")
#define WAITV0() asm volatile("s_waitcnt vmcnt(0)" ::: "memory")

#define STG(buf, mat, h, kt) { \
    const u16* _s0 = ((mat) ? srcB[(h)*2]     : srcA[(h)*2])     + (size_t)(kt) * 64; \
    const u16* _s1 = ((mat) ? srcB[(h)*2 + 1] : srcA[(h)*2 + 1]) + (size_t)(kt) * 64; \
    char* _d = (char*)&ls[buf][mat][0]; \
    __builtin_amdgcn_global_load_lds((gvoid_t*)_s0, (lvoid_t*)(_d + (h)*16384 + tid*16), 16, 0, 0); \
    __builtin_amdgcn_global_load_lds((gvoid_t*)_s1, (lvoid_t*)(_d + (h)*16384 + 8192 + tid*16), 16, 0, 0); }

#define QUAD(buf, kk, mih) { \
    const char* _pa = (const char*)&ls[buf][0][0]; \
    const char* _pb = (const char*)&ls[buf][1][0]; \
    bf16x8 _af[4], _bf[4]; \
    _Pragma("unroll") \
    for (int _m = 0; _m < 4; ++_m) \
        _af[_m] = *(const bf16x8*)(_pa + abase + ((mih)*4 + _m) * 2048 + (kk) * 1024); \
    _Pragma("unroll") \
    for (int _n = 0; _n < 4; ++_n) \
        _bf[_n] = *(const bf16x8*)(_pb + bbase + _n * 2048 + (kk) * 1024); \
    __builtin_amdgcn_s_setprio(1); \
    _Pragma("unroll") \
    for (int _m = 0; _m < 4; ++_m) \
        _Pragma("unroll") \
        for (int _n = 0; _n < 4; ++_n) \
            acc[(mih)*4 + _m][_n] = __builtin_amdgcn_mfma_f32_16x16x32_bf16(_af[_m], _bf[_n], acc[(mih)*4 + _m][_n], 0, 0, 0); \
    __builtin_amdgcn_s_setprio(0); }

__global__ __launch_bounds__(512, 2)
void k_gemm256(const u16* __restrict__ A, int lda,
               const u16* __restrict__ B, int ldb,
               float* __restrict__ C, int ldc,
               int ntm, int Nstore, int K) {
    __shared__ u16 ls[2][2][256 * 64];     // 128 KiB
    const int tid = threadIdx.x;
    const int lane = tid & 63, wid = tid >> 6;
    const int wr = wid >> 2, wc = wid & 3;

    // bijective XCD swizzle
    int nwg = gridDim.x, bid = blockIdx.x;
    int q8 = nwg >> 3, r8 = nwg & 7;
    int xcd = bid & 7, linb = bid >> 3;
    int sb = (xcd < r8 ? xcd * (q8 + 1) : r8 * (q8 + 1) + (xcd - r8) * q8) + linb;
    int mt = sb % ntm, nt = sb / ntm;

    const u16* Ablk = A + (size_t)(mt * 256) * lda;
    const u16* Bblk = B + (size_t)(nt * 256) * ldb;

    // staging sources: dest byte p = s*8192 + tid*16 (linear); logical = unswizzle(p)
    const u16* srcA[4]; const u16* srcB[4];
    #pragma unroll
    for (int s = 0; s < 4; ++s) {
        int p = s * 8192 + tid * 16;
        int qq = p ^ (((p >> 9) & 1) << 5);
        int sub = qq >> 10, rin = (qq >> 6) & 15, cby = qq & 63;
        int row = ((sub >> 1) << 4) | rin;
        int col = ((((sub & 1) << 6) | cby)) >> 1;
        srcA[s] = Ablk + (size_t)row * lda + col;
        srcB[s] = Bblk + (size_t)row * ldb + col;
    }
    // read-side swizzled base offsets (mi adds 2048B, kk adds 1024B)
    int l15 = lane & 15;
    int lowb = (l15 * 64 + ((lane >> 4) << 4)) ^ (((l15 >> 3) & 1) << 5);
    int abase = wr * 16384 + lowb;
    int bbase = wc * 8192  + lowb;

    f32x4 acc[8][4] = {};
    int nk = K >> 6, nit = nk >> 1;

    // prologue: tile 0 -> buf0 (8 loads)
    STG(0, 0, 0, 0); STG(0, 0, 1, 0); STG(0, 1, 0, 0); STG(0, 1, 1, 0);

    for (int i = 0; i < nit; ++i) {
        int t1 = 2 * i + 1, t2 = 2 * i + 2;
        bool more = (i + 1 < nit);
        // ph0
        STG(1, 0, 0, t1);
        WAITV2(); BAR();
        QUAD(0, 0, 0); BAR();
        // ph1
        STG(1, 0, 1, t1);
        QUAD(0, 0, 1); BAR();
        // ph2
        STG(1, 1, 0, t1);
        QUAD(0, 1, 0); BAR();
        // ph3
        STG(1, 1, 1, t1);
        QUAD(0, 1, 1); BAR();
        // ph4
        if (more) { STG(0, 0, 0, t2); WAITV2(); } else { WAITV0(); }
        BAR();
        QUAD(1, 0, 0); BAR();
        // ph5
        if (more) STG(0, 0, 1, t2);
        QUAD(1, 0, 1); BAR();
        // ph6
        if (more) STG(0, 1, 0, t2);
        QUAD(1, 1, 0); BAR();
        // ph7
        if (more) STG(0, 1, 1, t2);
        QUAD(1, 1, 1); BAR();
    }

    int rb = (lane >> 4) * 4, cc = lane & 15;
    int mrow = mt * 256 + wr * 128, ncol = nt * 256 + wc * 64;
    #pragma unroll
    for (int mi = 0; mi < 8; ++mi) {
        #pragma unroll
        for (int ni = 0; ni < 4; ++ni) {
            int gc = ncol + ni * 16 + cc;
            if (gc < Nstore) {
                #pragma unroll
                for (int rr = 0; rr < 4; ++rr) {
                    size_t off = (size_t)(mrow + mi * 16 + rb + rr) * ldc + gc;
                    C[off] = acc[mi][ni][rr];
                }
            }
        }
    }
}

// ---------------- launch ----------------
extern "C" void kernel_launch(void* const* d_in, const int* in_sizes, int n_in,
                              void* d_out, int out_size, void* d_ws, size_t ws_size,
                              hipStream_t stream) {
    const int*   ids   = (const int*)d_in[0];
    const float* emb   = (const float*)d_in[1];
    const float* lmw   = (const float*)d_in[2];
    const float* normw = (const float*)d_in[3];
    const float* lnw   = (const float*)d_in[4];
    const float* lskip = (const float*)d_in[5];
    const float* linw  = (const float*)d_in[6];
    const float* lcw   = (const float*)d_in[7];
    const float* lcb   = (const float*)d_in[8];
    const float* lWd1  = (const float*)d_in[9];
    const float* lWd2  = (const float*)d_in[10];
    const float* lWd2b = (const float*)d_in[11];
    const float* lWB   = (const float*)d_in[12];
    const float* lWC   = (const float*)d_in[13];
    const float* lAlog = (const float*)d_in[14];
    const float* lWD   = (const float*)d_in[15];
    const float* loutw = (const float*)d_in[16];
    float* out = (float*)d_out;

    char* ws = (char*)d_ws;
    size_t off = 0;
    auto alloc = [&](size_t bytes) { char* p = ws + off; off += (bytes + 255) & ~(size_t)255; return p; };
    u16*   lm_bf    = (u16*)  alloc((size_t)VPAD * 1024 * 2);
    u16*   wsi_bf   = (u16*)  alloc((size_t)NL * 4096 * Dd_ * 2);   // [skip;in] concat
    u16*   wout_bf  = (u16*)  alloc((size_t)NL * Dd_ * Ed * 2);
    u16*   wd2_bf   = (u16*)  alloc((size_t)NL * Ed * 64 * 2);
    u16*   wsml_bf  = (u16*)  alloc((size_t)NL * 128 * Ed * 2);
    float* resid    = (float*)alloc((size_t)TOK * Dd_ * 4);
    u16*   xn_bf    = (u16*)  alloc((size_t)TOK * Dd_ * 2);
    u16*   xall_bf  = (u16*)  alloc((size_t)TOK * XLD * 2);         // cols 0-2047 skip, 2048-4095 xin (bf16)
    u16*   xbf      = (u16*)  alloc((size_t)TOK * Ed * 2);
    float* xs       = (float*)alloc((size_t)TOK * 128 * 4);
    u16*   xs_bf    = (u16*)  alloc((size_t)TOK * 128 * 2);
    float* xs_part  = (float*)alloc((size_t)8 * TOK * 128 * 4);
    float* opart    = (float*)alloc((size_t)2 * TOK * Dd_ * 4);
    float* delta    = (float*)alloc((size_t)TOK * Ed * 4);
    float* sumd     = (float*)alloc((size_t)NCHUNK * Bd * Ed * 4);
    float* Hc       = (float*)alloc((size_t)NCHUNK * Bd * Ed * Nd * 4);
    u16*   ybf      = (u16*)  alloc((size_t)TOK * Ed * 2);
    (void)ws_size; (void)in_sizes; (void)n_in; (void)out_size;

    // all weight conversions in one dispatch (8 floats/thread)
    k_convert_all<<<31744, 256, 0, stream>>>(lmw, lskip, linw, loutw, lWd2, lWd1, lWB, lWC,
                                             lm_bf, wsi_bf, wout_bf, wd2_bf, wsml_bf);

    // embedding + layer-0 norm
    k_embed_norm<<<TOK, 256, 0, stream>>>(ids, emb, lnw, resid, xn_bf);

    for (int lyr = 0; lyr < NL; ++lyr) {
        const float* Alog = lAlog + (size_t)lyr * Ed * Nd;
        // [skip | xin] = xn @ [skip_w; in_w]^T  -> bf16 (M=2048, N=4096, K=1024)
        k_gemm_bt<3><<<dim3(16 * 32, 1, 1), 256, 0, stream>>>(xn_bf, Dd_,
            wsi_bf + (size_t)lyr * 4096 * Dd_, Dd_, (float*)xall_bf, XLD, nullptr,
            16, 4096, 1024, 0);
        k_conv_silu<<<TOK * 2, 256, 0, stream>>>(xall_bf + Ed, lcw + (size_t)lyr * Ed * 4,
                                                 lcb + (size_t)lyr * Ed, xbf);
        // xs_part[c] = x @ [Wd1;WB;WC]^T  split-K (8 chunks of 256)
        k_gemm_bt<0><<<dim3(16, 1, 8), 256, 0, stream>>>(xbf, Ed,
            wsml_bf + (size_t)lyr * 128 * Ed, Ed, xs_part, 128, nullptr, 16, 128, 256,
            (size_t)TOK * 128);
        k_reduce_xs<<<TOK * 128 / 4 / 256, 256, 0, stream>>>(xs_part, xs, xs_bf);
        // delta = softplus(xd @ Wd2^T + b)  (epilogue-fused)
        k_gemm_bt<2><<<dim3(16 * 16, 1, 1), 256, 0, stream>>>(xs_bf, 128,
            wd2_bf + (size_t)lyr * Ed * 64, 64, delta, Ed, lWd2b + (size_t)lyr * Ed,
            16, Ed, 64, 0);
        // chunked scan (transposed; combine fused into pass2)
        k_scan_pass1<<<NCHUNK * Bd * Ed / 256, 256, 0, stream>>>(delta, xbf, xs, Alog, sumd, Hc);
        k_scan_pass2<<<NCHUNK * Bd * Ed / 256, 256, 0, stream>>>(delta, xbf, xs, Alog,
            sumd, Hc, lWD + (size_t)lyr * Ed, xall_bf, ybf);
        // opart[z] = y @ out_w^T (split-K z=2), then resid += p0+p1 and next norm
        k_gemm_bt<0><<<dim3(16 * 8, 1, 2), 256, 0, stream>>>(ybf, Ed,
            wout_bf + (size_t)lyr * Dd_ * Ed, Ed, opart, Dd_, nullptr, 16, Dd_, 1024,
            (size_t)TOK * Dd_);
        const float* nw = (lyr == NL - 1) ? normw : lnw + (size_t)(lyr + 1) * Dd_;
        k_add2_norm<<<TOK, 256, 0, stream>>>(opart, resid, nw, xn_bf);
    }

    // lm_head (256^2 8-phase)
    k_gemm256<<<dim3(8 * (VPAD / 256), 1, 1), 512, 0, stream>>>(xn_bf, Dd_, lm_bf, Dd_,
        out, VREAL, 8, VREAL, 1024);
}